// Round 4
// baseline (62.945 us; speedup 1.0000x reference)
//
#include <hip/hip_runtime.h>

// Problem constants
#define BATCH 512
#define INFEAT 4096
#define LOUT 1023   // code_length - 1
#define NCLS 1000
#define NPAD 1024
#define SPLITK 8
#define NBLK 512    // gemm grid size; 2 blocks/CU x 256 CU -> all co-resident

typedef __bf16 bf16x8 __attribute__((ext_vector_type(8)));
typedef float f32x4 __attribute__((ext_vector_type(4)));

// round-to-nearest-even f32 -> bf16 (bit trick)
__device__ __forceinline__ unsigned short f2bf(float a) {
    unsigned u = __builtin_bit_cast(unsigned, a);
    return (unsigned short)((u + 0x7fffu + ((u >> 16) & 1u)) >> 16);
}
__device__ __forceinline__ unsigned f2bf2(float a, float b) {
    return (unsigned)f2bf(a) | ((unsigned)f2bf(b) << 16);
}
__device__ __forceinline__ float bf2f(unsigned short u) {
    return __builtin_bit_cast(float, ((unsigned)u) << 16);
}

__device__ __forceinline__ void gload_lds16(const void* g, void* l) {
    __builtin_amdgcn_global_load_lds(
        (const __attribute__((address_space(1))) void*)g,
        (__attribute__((address_space(3))) void*)l, 16, 0, 0);
}

// ---------------- fused convert: x and W -> pre-swizzled bf16 ----------------
// Layout: row-major, row stride 8192B. Within each 128B (64-elem) K-chunk,
// 16B granule at slot s holds logical granule (s ^ (row&7)) — inverse of the
// XOR applied at ds_read time, so global->LDS staging is a linear copy.
__global__ __launch_bounds__(256) void k_cvt(const float* __restrict__ x,
                                             const float* __restrict__ W,
                                             unsigned char* __restrict__ xb,
                                             unsigned char* __restrict__ Wb,
                                             int* __restrict__ done) {
    int blk = blockIdx.x;
    if (blk == 0 && threadIdx.x == 0) *done = 0;  // grid-barrier counter init
    if (blk < 1024) {                          // x: 512 rows x 512 granules
        int g = blk * 256 + threadIdx.x;
        int r = g >> 9, k16 = g & 511;
        const float4* p = (const float4*)(x + (size_t)r * INFEAT + k16 * 8);
        float4 v0 = p[0], v1 = p[1];
        uint4 o;
        o.x = f2bf2(v0.x, v0.y); o.y = f2bf2(v0.z, v0.w);
        o.z = f2bf2(v1.x, v1.y); o.w = f2bf2(v1.z, v1.w);
        *(uint4*)(xb + (size_t)r * 8192 + (k16 >> 3) * 128 + (((k16 & 7) ^ (r & 7)) * 16)) = o;
    } else {                                    // W: 1024 rows x 512 granules
        int g = (blk - 1024) * 256 + threadIdx.x;
        int r = g >> 9, k16 = g & 511;
        uint4 o = {0, 0, 0, 0};
        if (r < LOUT) {
            const float4* p = (const float4*)(W + (size_t)r * INFEAT + k16 * 8);
            float4 v0 = p[0], v1 = p[1];
            o.x = f2bf2(v0.x, v0.y); o.y = f2bf2(v0.z, v0.w);
            o.z = f2bf2(v1.x, v1.y); o.w = f2bf2(v1.z, v1.w);
        }
        *(uint4*)(Wb + (size_t)r * 8192 + (k16 >> 3) * 128 + (((k16 & 7) ^ (r & 7)) * 16)) = o;
    }
}

// ---------------- mono kernel: GEMM (split-K) -> grid barrier -> FWHT row ----
// GEMM: BM=128, BN=64, BK=64, SK=8 -> 512 blocks. Chunked XCD swizzle puts one
// full sp-slice (1.5 MB working set) on each XCD's L2. 3-buffer LDS pipeline
// with counted vmcnt (2-deep prefetch; loads stay in flight across barriers).
// After a device-wide barrier, block `work` finishes row r=work:
// reduce SK + bias + tanh + FWHT (dot with Hadamard codes) + inv + normalize.
__global__ __launch_bounds__(256, 2) void k_gemm_fused(
    const unsigned char* __restrict__ xb, const unsigned char* __restrict__ Wb,
    unsigned short* __restrict__ partial, const float* __restrict__ bias,
    const float* __restrict__ epsp, const float* __restrict__ powp,
    float* __restrict__ out, int* __restrict__ done) {
    extern __shared__ __align__(16) unsigned char smem[];
    unsigned char* lds = smem;                  // 3 x 24576 = 73728 B
    float* g = (float*)(smem + 73728);          // 1024 f32
    float* wsum = (float*)(smem + 77824);       // 4 f32

    const int bid = blockIdx.x;
    const int work = (bid & 7) * 64 + (bid >> 3);   // chunked XCD swizzle
    const int bn = work & 15, bm = (work >> 4) & 3, sp = work >> 6;
    const int tid = threadIdx.x;
    const int wave = tid >> 6, lane = tid & 63;
    const int lrow = lane & 15, lgrp = lane >> 4;
    const int wr = wave >> 1, wc = wave & 1;
    const int arow0 = bm * 128, brow0 = bn * 64, chunk0 = sp * 8;

    f32x4 acc[4][2] = {};

    auto STAGE = [&](int bsel, int c) {
        unsigned char* lA = lds + bsel * 24576;
        unsigned char* lB = lA + 16384;
#pragma unroll
        for (int rr = 0; rr < 4; ++rr) {       // A: 128 rows = 1024 granules
            int gg = rr * 256 + tid;
            int r = gg >> 3, s = gg & 7;
            gload_lds16(xb + (size_t)(arow0 + r) * 8192 + c * 128 + s * 16,
                        lA + (rr * 256 + wave * 64) * 16);
        }
#pragma unroll
        for (int rr = 0; rr < 2; ++rr) {       // B: 64 rows = 512 granules
            int gg = rr * 256 + tid;
            int r = gg >> 3, s = gg & 7;
            gload_lds16(Wb + (size_t)(brow0 + r) * 8192 + c * 128 + s * 16,
                        lB + (rr * 256 + wave * 64) * 16);
        }
    };

    auto COMPUTE = [&](int bsel) {
        const unsigned char* lA = lds + bsel * 24576;
        const unsigned char* lB = lA + 16384;
#pragma unroll
        for (int ks = 0; ks < 2; ++ks) {
            int swz = ((ks * 4 + lgrp) ^ (lrow & 7)) * 16;
            bf16x8 a[4], b[2];
#pragma unroll
            for (int m = 0; m < 4; ++m)
                a[m] = *(const bf16x8*)(lA + (wr * 64 + m * 16 + lrow) * 128 + swz);
#pragma unroll
            for (int n = 0; n < 2; ++n)
                b[n] = *(const bf16x8*)(lB + (wc * 32 + n * 16 + lrow) * 128 + swz);
#pragma unroll
            for (int m = 0; m < 4; ++m)
#pragma unroll
                for (int n = 0; n < 2; ++n)
                    acc[m][n] = __builtin_amdgcn_mfma_f32_16x16x32_bf16(
                        a[m], b[n], acc[m][n], 0, 0, 0);
        }
    };

    // --- pipelined K-loop: 8 steps, 2-deep prefetch, counted vmcnt ---
    STAGE(0, chunk0);
    STAGE(1, chunk0 + 1);
#pragma unroll 1
    for (int t = 0; t < 8; ++t) {
        if (t < 6) {
            STAGE((t + 2) % 3, chunk0 + t + 2);
            // stages t, t+1, t+2 may be in flight (6 loads each); wait stage t
            asm volatile("s_waitcnt vmcnt(12)" ::: "memory");
        } else if (t == 6) {
            asm volatile("s_waitcnt vmcnt(6)" ::: "memory");
        } else {
            asm volatile("s_waitcnt vmcnt(0)" ::: "memory");
        }
        __builtin_amdgcn_s_barrier();           // buf t ready for all waves
        asm volatile("" ::: "memory");
        COMPUTE(t % 3);
        asm volatile("s_waitcnt lgkmcnt(0)" ::: "memory");  // reads retired
        __builtin_amdgcn_s_barrier();           // buf t free for re-stage
        asm volatile("" ::: "memory");
    }

    // --- epilogue: bf16 partials ---
    unsigned short* P = partial + (size_t)sp * (BATCH * NPAD);
#pragma unroll
    for (int m = 0; m < 4; ++m)
#pragma unroll
        for (int n = 0; n < 2; ++n)
#pragma unroll
            for (int reg = 0; reg < 4; ++reg) {
                int r = arow0 + wr * 64 + m * 16 + lgrp * 4 + reg;
                int c = brow0 + wc * 32 + n * 16 + lrow;
                P[(size_t)r * NPAD + c] = f2bf(acc[m][n][reg]);
            }

    // --- device-wide barrier (all 512 blocks co-resident by construction) ---
    __syncthreads();                      // drain this block's stores
    if (tid == 0) {
        __threadfence();                  // release: writeback to device scope
        atomicAdd(done, 1);
        while (__hip_atomic_load(done, __ATOMIC_RELAXED,
                                 __HIP_MEMORY_SCOPE_AGENT) < NBLK)
            __builtin_amdgcn_s_sleep(1);
        __threadfence();                  // acquire: invalidate L1/L2
    }
    __syncthreads();

    // --- fused finish for row r = work ---
    const int r = work;
    const int n0 = tid * 4;

    f32x4 v = {0.0f, 0.0f, 0.0f, 0.0f};
#pragma unroll
    for (int s = 0; s < SPLITK; ++s) {
        ushort4 p = *(const ushort4*)(partial + ((size_t)s * BATCH + r) * NPAD + n0);
        v[0] += bf2f(p.x); v[1] += bf2f(p.y); v[2] += bf2f(p.z); v[3] += bf2f(p.w);
    }
    float bb[4];
    if (tid < 255) {
        float4 b4 = *(const float4*)(bias + n0);
        bb[0] = b4.x; bb[1] = b4.y; bb[2] = b4.z; bb[3] = b4.w;
    } else {
        bb[0] = bias[1020]; bb[1] = bias[1021]; bb[2] = bias[1022]; bb[3] = 0.0f;
    }
    // h = tanh(dot + b), stored shifted by +1 into g (g[0]=0 handles the
    // dropped first Hadamard column: dot[c] = FWHT(g)[c], H symmetric)
    if (tid == 0) g[0] = 0.0f;
#pragma unroll
    for (int j = 0; j < 4; ++j) {
        int n = n0 + j;
        if (n < LOUT) g[n + 1] = tanhf(v[j] + bb[j]);
    }
    __syncthreads();

    // FWHT: 10 stages, 512 butterflies/stage, 2 per thread
#pragma unroll 1
    for (int s = 0; s < 10; ++s) {
        int st = 1 << s;
#pragma unroll
        for (int pp = 0; pp < 2; ++pp) {
            int p = tid + pp * 256;
            int idx = ((p >> s) << (s + 1)) | (p & (st - 1));
            float a = g[idx], c = g[idx + st];
            g[idx] = a + c;
            g[idx + st] = a - c;
        }
        __syncthreads();
    }

    // inv = 1/max(1023 - dot, eps)^pw ; zero padded classes; normalize
    const float eps = *epsp, pw = *powp;
    float iv[4];
    float ss = 0.0f;
#pragma unroll
    for (int j = 0; j < 4; ++j) {
        int c = n0 + j;
        float d = fmaxf(1023.0f - g[c], eps);
        float q = (pw == 1.0f) ? (1.0f / d) : powf(d, -pw);
        if (c >= NCLS) q = 0.0f;
        iv[j] = q;
        ss += q;
    }
#pragma unroll
    for (int m = 32; m; m >>= 1) ss += __shfl_xor(ss, m, 64);
    if ((tid & 63) == 0) wsum[tid >> 6] = ss;
    __syncthreads();
    float sc = 1.0f / (wsum[0] + wsum[1] + wsum[2] + wsum[3]);

    if (n0 < NCLS) {  // NCLS = 1000 = 4*250: threads 0..249 store full float4
        float4 o;
        o.x = iv[0] * sc; o.y = iv[1] * sc; o.z = iv[2] * sc; o.w = iv[3] * sc;
        *(float4*)(out + (size_t)r * NCLS + n0) = o;
    }
}

extern "C" void kernel_launch(void* const* d_in, const int* in_sizes, int n_in,
                              void* d_out, int out_size, void* d_ws, size_t ws_size,
                              hipStream_t stream) {
    const float* x = (const float*)d_in[0];       // (512, 4096)
    const float* W = (const float*)d_in[1];       // (1023, 4096)
    const float* b = (const float*)d_in[2];       // (1023,)
    // d_in[3] = labels: NOT needed (Hadamard structure -> FWHT)
    const float* epsp = (const float*)d_in[4];
    const float* powp = (const float*)d_in[5];
    float* out = (float*)d_out;                   // (512, 1000)

    unsigned char* ws = (unsigned char*)d_ws;
    unsigned char* xb = ws;                          // 4 MB (512 x 4096 bf16, swz)
    unsigned char* Wb = ws + (4u << 20);             // 8 MB (1024 x 4096 bf16, swz)
    unsigned short* partial = (unsigned short*)(ws + (12u << 20));  // 8 MB
    int* done = (int*)(ws + (20u << 20));            // grid-barrier counter

    k_cvt<<<3072, 256, 0, stream>>>(x, W, xb, Wb, done);
    k_gemm_fused<<<NBLK, 256, 77840, stream>>>(xb, Wb, partial, b, epsp, powp,
                                               out, done);
}

// Round 5
// 26.829 us; speedup vs baseline: 2.3462x; 2.3462x over previous
//
#include <hip/hip_runtime.h>

// Problem constants
#define BATCH 512
#define INFEAT 4096
#define LOUT 1023   // code_length - 1
#define NCLS 1000
#define NPAD 1024
#define SPLITK 8

typedef __bf16 bf16x8 __attribute__((ext_vector_type(8)));
typedef float f32x4 __attribute__((ext_vector_type(4)));

// round-to-nearest-even f32 -> bf16 (bit trick) for the partial store
__device__ __forceinline__ unsigned short f2bf(float a) {
    unsigned u = __builtin_bit_cast(unsigned, a);
    return (unsigned short)((u + 0x7fffu + ((u >> 16) & 1u)) >> 16);
}
__device__ __forceinline__ float bf2f(unsigned short u) {
    return __builtin_bit_cast(float, ((unsigned)u) << 16);
}

// pack 8 f32 -> 8 bf16 (compiler emits v_cvt_pk_bf16_f32 pairs)
__device__ __forceinline__ uint4 pack8(float4 a, float4 b) {
    union { __bf16 h[8]; uint4 u; } r;
    r.h[0] = (__bf16)a.x; r.h[1] = (__bf16)a.y;
    r.h[2] = (__bf16)a.z; r.h[3] = (__bf16)a.w;
    r.h[4] = (__bf16)b.x; r.h[5] = (__bf16)b.y;
    r.h[6] = (__bf16)b.z; r.h[7] = (__bf16)b.w;
    return r.u;
}

// ---------------- GEMM: partial[s] = bf16(x) @ bf16(W)^T (split-K) ----------
// BM=128, BN=64, BK=64, SK=8 -> 512 blocks = 2/CU. Chunked XCD swizzle: each
// XCD owns one sp-slice (3 MB f32 working set -> L2-resident re-reads).
// Reg-staged conversion: global f32 loads issued BEFORE COMPUTE (latency
// hidden under MFMA), cvt+swizzled ds_write after, 1 barrier/step.
// LDS layout per tile: row stride 128B; 16B granule slot s holds logical
// granule s^(row&7); COMPUTE reads slot (ks*4+lgrp)^(lrow&7).
__global__ __launch_bounds__(256, 2) void k_gemm(
    const float* __restrict__ x, const float* __restrict__ W,
    unsigned short* __restrict__ partial) {
    __shared__ unsigned char lds[49152];      // 2 x (16KB A + 8KB B)
    const int bid = blockIdx.x;
    const int work = (bid & 7) * 64 + (bid >> 3);   // chunked XCD swizzle
    const int bn = work & 15, bm = (work >> 4) & 3, sp = work >> 6;
    const int tid = threadIdx.x;
    const int wave = tid >> 6, lane = tid & 63;
    const int lrow = lane & 15, lgrp = lane >> 4;
    const int wr = wave >> 1, wc = wave & 1;
    const int arow0 = bm * 128, brow0 = bn * 64, chunk0 = sp * 8;

    f32x4 acc[4][2] = {};
    float4 ar[4][2], br[2][2];

    auto LOADR = [&](int t) {
        const int c = chunk0 + t;
#pragma unroll
        for (int rr = 0; rr < 4; ++rr) {      // A: 128 rows x 8 granules
            int g = rr * 256 + tid;
            int row = g >> 3, j = g & 7;
            const float4* p = (const float4*)(x + (size_t)(arow0 + row) * INFEAT
                                              + c * 64 + j * 8);
            ar[rr][0] = p[0]; ar[rr][1] = p[1];
        }
#pragma unroll
        for (int rr = 0; rr < 2; ++rr) {      // B: 64 rows x 8 granules
            int g = rr * 256 + tid;
            int row = g >> 3, j = g & 7;
            int wrow = brow0 + row;
            if (wrow < LOUT) {
                const float4* p = (const float4*)(W + (size_t)wrow * INFEAT
                                                  + c * 64 + j * 8);
                br[rr][0] = p[0]; br[rr][1] = p[1];
            } else {                          // pad row 1023 with zeros
                br[rr][0] = make_float4(0.f, 0.f, 0.f, 0.f);
                br[rr][1] = make_float4(0.f, 0.f, 0.f, 0.f);
            }
        }
    };

    auto WRITE = [&](int bsel) {
        unsigned char* lA = lds + bsel * 24576;
        unsigned char* lB = lA + 16384;
#pragma unroll
        for (int rr = 0; rr < 4; ++rr) {
            int g = rr * 256 + tid;
            int row = g >> 3, j = g & 7;
            *(uint4*)(lA + row * 128 + ((j ^ (row & 7)) * 16)) =
                pack8(ar[rr][0], ar[rr][1]);
        }
#pragma unroll
        for (int rr = 0; rr < 2; ++rr) {
            int g = rr * 256 + tid;
            int row = g >> 3, j = g & 7;
            *(uint4*)(lB + row * 128 + ((j ^ (row & 7)) * 16)) =
                pack8(br[rr][0], br[rr][1]);
        }
    };

    auto COMPUTE = [&](int bsel) {
        const unsigned char* lA = lds + bsel * 24576;
        const unsigned char* lB = lA + 16384;
#pragma unroll
        for (int ks = 0; ks < 2; ++ks) {
            int swz = ((ks * 4 + lgrp) ^ (lrow & 7)) * 16;
            bf16x8 a[4], b[2];
#pragma unroll
            for (int m = 0; m < 4; ++m)
                a[m] = *(const bf16x8*)(lA + (wr * 64 + m * 16 + lrow) * 128 + swz);
#pragma unroll
            for (int n = 0; n < 2; ++n)
                b[n] = *(const bf16x8*)(lB + (wc * 32 + n * 16 + lrow) * 128 + swz);
#pragma unroll
            for (int m = 0; m < 4; ++m)
#pragma unroll
                for (int n = 0; n < 2; ++n)
                    acc[m][n] = __builtin_amdgcn_mfma_f32_16x16x32_bf16(
                        a[m], b[n], acc[m][n], 0, 0, 0);
        }
    };

    LOADR(0);
    WRITE(0);
    __syncthreads();
#pragma unroll 1
    for (int t = 0; t < 8; ++t) {
        if (t + 1 < 8) LOADR(t + 1);          // issue early: hide under MFMA
        COMPUTE(t & 1);
        if (t + 1 < 8) WRITE((t + 1) & 1);    // write late: other buffer
        __syncthreads();
    }

    unsigned short* P = partial + (size_t)sp * (BATCH * NPAD);
#pragma unroll
    for (int m = 0; m < 4; ++m)
#pragma unroll
        for (int n = 0; n < 2; ++n)
#pragma unroll
            for (int reg = 0; reg < 4; ++reg) {
                int r = arow0 + wr * 64 + m * 16 + lgrp * 4 + reg;
                int c = brow0 + wc * 32 + n * 16 + lrow;
                P[(size_t)r * NPAD + c] = f2bf(acc[m][n][reg]);
            }
}

// ---------------- fused: split-K reduce + bias + tanh + FWHT + inv + norm ----
// One block per batch row. dot[c] = sum_j h[j]*H[c][j+1] = FWHT(g)[c] with
// g[0]=0, g[k]=h[k-1]  (Sylvester H is symmetric; H[c][0]=1 * g[0]=0 drops out).
__global__ __launch_bounds__(256) void k_fused(const unsigned short* __restrict__ partial,
                                               const float* __restrict__ bias,
                                               const float* __restrict__ epsp,
                                               const float* __restrict__ powp,
                                               float* __restrict__ out) {
    __shared__ float g[1024];
    __shared__ float wsum[4];
    const int r = blockIdx.x, t = threadIdx.x;
    const int n0 = t * 4;

    // split-K reduce (bf16 partials -> f32)
    f32x4 v = {0.0f, 0.0f, 0.0f, 0.0f};
#pragma unroll
    for (int s = 0; s < SPLITK; ++s) {
        ushort4 p = *(const ushort4*)(partial + ((size_t)s * BATCH + r) * NPAD + n0);
        v[0] += bf2f(p.x); v[1] += bf2f(p.y); v[2] += bf2f(p.z); v[3] += bf2f(p.w);
    }
    // bias (guard the tail: bias has 1023 elems)
    float bb[4];
    if (t < 255) {
        float4 b4 = *(const float4*)(bias + n0);
        bb[0] = b4.x; bb[1] = b4.y; bb[2] = b4.z; bb[3] = b4.w;
    } else {
        bb[0] = bias[1020]; bb[1] = bias[1021]; bb[2] = bias[1022]; bb[3] = 0.0f;
    }
    // h = tanh(dot + b), stored shifted by +1 into g
    if (t == 0) g[0] = 0.0f;
#pragma unroll
    for (int j = 0; j < 4; ++j) {
        int n = n0 + j;
        if (n < LOUT) g[n + 1] = tanhf(v[j] + bb[j]);
    }
    __syncthreads();

    // FWHT: 10 stages, 512 butterflies/stage, 2 per thread
#pragma unroll 1
    for (int s = 0; s < 10; ++s) {
        int st = 1 << s;
#pragma unroll
        for (int pp = 0; pp < 2; ++pp) {
            int p = t + pp * 256;
            int idx = ((p >> s) << (s + 1)) | (p & (st - 1));
            float a = g[idx], c = g[idx + st];
            g[idx] = a + c;
            g[idx + st] = a - c;
        }
        __syncthreads();
    }

    // inv = 1/max(1023 - dot, eps)^pw ; zero padded classes; normalize
    const float eps = *epsp, pw = *powp;
    float iv[4];
    float ss = 0.0f;
#pragma unroll
    for (int j = 0; j < 4; ++j) {
        int c = n0 + j;
        float d = fmaxf(1023.0f - g[c], eps);
        float q = (pw == 1.0f) ? (1.0f / d) : powf(d, -pw);
        if (c >= NCLS) q = 0.0f;
        iv[j] = q;
        ss += q;
    }
#pragma unroll
    for (int m = 32; m; m >>= 1) ss += __shfl_xor(ss, m, 64);
    if ((t & 63) == 0) wsum[t >> 6] = ss;
    __syncthreads();
    float sc = 1.0f / (wsum[0] + wsum[1] + wsum[2] + wsum[3]);

    if (n0 < NCLS) {  // NCLS = 1000 = 4*250: threads 0..249 store full float4
        float4 o;
        o.x = iv[0] * sc; o.y = iv[1] * sc; o.z = iv[2] * sc; o.w = iv[3] * sc;
        *(float4*)(out + (size_t)r * NCLS + n0) = o;
    }
}

extern "C" void kernel_launch(void* const* d_in, const int* in_sizes, int n_in,
                              void* d_out, int out_size, void* d_ws, size_t ws_size,
                              hipStream_t stream) {
    const float* x = (const float*)d_in[0];       // (512, 4096)
    const float* W = (const float*)d_in[1];       // (1023, 4096)
    const float* b = (const float*)d_in[2];       // (1023,)
    // d_in[3] = labels: NOT needed (Hadamard structure -> FWHT)
    const float* epsp = (const float*)d_in[4];
    const float* powp = (const float*)d_in[5];
    float* out = (float*)d_out;                   // (512, 1000)

    unsigned char* ws = (unsigned char*)d_ws;
    unsigned short* partial = (unsigned short*)ws;  // 8 MB (8 x 512 x 1024 bf16)

    k_gemm<<<512, 256, 0, stream>>>(x, W, partial);
    k_fused<<<512, 256, 0, stream>>>(partial, b, epsp, powp, out);
}

// Round 6
// 25.921 us; speedup vs baseline: 2.4283x; 1.0350x over previous
//
#include <hip/hip_runtime.h>

// Problem constants
#define BATCH 512
#define INFEAT 4096
#define LOUT 1023   // code_length - 1
#define NCLS 1000
#define NPAD 1024
#define SPLITK 8

typedef __bf16 bf16x8 __attribute__((ext_vector_type(8)));
typedef float f32x4 __attribute__((ext_vector_type(4)));

__device__ __forceinline__ unsigned short f2bf(float a) {
    unsigned u = __builtin_bit_cast(unsigned, a);
    return (unsigned short)((u + 0x7fffu + ((u >> 16) & 1u)) >> 16);
}
__device__ __forceinline__ float bf2f(unsigned short u) {
    return __builtin_bit_cast(float, ((unsigned)u) << 16);
}
// pack 8 f32 -> 8 bf16 (v_cvt_pk_bf16_f32 pairs)
__device__ __forceinline__ uint4 pack8(float4 a, float4 b) {
    union { __bf16 h[8]; uint4 u; } r;
    r.h[0] = (__bf16)a.x; r.h[1] = (__bf16)a.y;
    r.h[2] = (__bf16)a.z; r.h[3] = (__bf16)a.w;
    r.h[4] = (__bf16)b.x; r.h[5] = (__bf16)b.y;
    r.h[6] = (__bf16)b.z; r.h[7] = (__bf16)b.w;
    return r.u;
}

// ---------------- GEMM: partial[s] = bf16(x) @ bf16(W)^T (split-K) ----------
// BM=128, BN=128, BK=64, SK=8 -> 256 blocks x 512 thr = 1 block/CU.
// 8 waves (2x4); per wave 64x32 output (acc[4][2]). Per K-step: 32 MFMA/wave,
// ONE raw s_barrier, lgkmcnt(0) only (never vmcnt(0) in-loop: counted
// vmcnt(8) waits only the set loaded >=2 steps ago). Ping-pong reg sets
// (sA/sB) stage f32 global -> cvt -> swizzled ds_write; loads issued 3 steps
// ahead. Chunked XCD swizzle: each XCD owns one sp-slice (3 MB, L2-resident).
__global__ __launch_bounds__(512, 1) void k_gemm(
    const float* __restrict__ x, const float* __restrict__ W,
    unsigned short* __restrict__ partial) {
    __shared__ unsigned char lds[65536];      // 2 x (16KB A + 16KB B)
    const int bid = blockIdx.x;
    const int work = (bid & 7) * 32 + (bid >> 3);   // chunked XCD swizzle
    const int bn = work & 7, bm = (work >> 3) & 3, sp = work >> 5;
    const int tid = threadIdx.x;
    const int wave = tid >> 6, lane = tid & 63;
    const int lrow = lane & 15, lgrp = lane >> 4;
    const int wr = wave >> 2, wc = wave & 3;        // 2 x 4 wave grid
    const int arow0 = bm * 128, brow0 = bn * 128, chunk0 = sp * 8;

    // per-thread staging coords (2 granule-pairs each for A and B)
    const int p0 = tid, p1 = 512 + tid;
    const int row0 = p0 >> 3, jb0 = p0 & 7;
    const int row1 = p1 >> 3, jb1 = p1 & 7;

    f32x4 acc[4][2] = {};
    float4 sAa[4], sAb[4], sBa[4], sBb[4];

    auto LOADR = [&](int t, float4 (&aa)[4], float4 (&bb)[4]) {
        const size_t c0 = (size_t)(chunk0 + t) * 64;
        {
            const float4* q = (const float4*)(x + (size_t)(arow0 + row0) * INFEAT + c0 + jb0 * 8);
            aa[0] = q[0]; aa[1] = q[1];
        }
        {
            const float4* q = (const float4*)(x + (size_t)(arow0 + row1) * INFEAT + c0 + jb1 * 8);
            aa[2] = q[0]; aa[3] = q[1];
        }
        {
            int wrow = brow0 + row0;
            if (wrow < LOUT) {
                const float4* q = (const float4*)(W + (size_t)wrow * INFEAT + c0 + jb0 * 8);
                bb[0] = q[0]; bb[1] = q[1];
            } else {
                bb[0] = make_float4(0.f, 0.f, 0.f, 0.f);
                bb[1] = make_float4(0.f, 0.f, 0.f, 0.f);
            }
        }
        {
            int wrow = brow0 + row1;
            if (wrow < LOUT) {
                const float4* q = (const float4*)(W + (size_t)wrow * INFEAT + c0 + jb1 * 8);
                bb[2] = q[0]; bb[3] = q[1];
            } else {
                bb[2] = make_float4(0.f, 0.f, 0.f, 0.f);
                bb[3] = make_float4(0.f, 0.f, 0.f, 0.f);
            }
        }
    };

    auto WRITE = [&](int bsel, float4 (&aa)[4], float4 (&bb)[4]) {
        unsigned char* lA = lds + bsel * 32768;
        unsigned char* lB = lA + 16384;
        *(uint4*)(lA + row0 * 128 + ((jb0 ^ (row0 & 7)) * 16)) = pack8(aa[0], aa[1]);
        *(uint4*)(lA + row1 * 128 + ((jb1 ^ (row1 & 7)) * 16)) = pack8(aa[2], aa[3]);
        *(uint4*)(lB + row0 * 128 + ((jb0 ^ (row0 & 7)) * 16)) = pack8(bb[0], bb[1]);
        *(uint4*)(lB + row1 * 128 + ((jb1 ^ (row1 & 7)) * 16)) = pack8(bb[2], bb[3]);
    };

    auto COMPUTE = [&](int bsel) {
        const unsigned char* lA = lds + bsel * 32768;
        const unsigned char* lB = lA + 16384;
        __builtin_amdgcn_s_setprio(1);
#pragma unroll
        for (int ks = 0; ks < 2; ++ks) {
            int swz = ((ks * 4 + lgrp) ^ (lrow & 7)) * 16;
            bf16x8 a[4], b[2];
#pragma unroll
            for (int m = 0; m < 4; ++m)
                a[m] = *(const bf16x8*)(lA + (wr * 64 + m * 16 + lrow) * 128 + swz);
#pragma unroll
            for (int n = 0; n < 2; ++n)
                b[n] = *(const bf16x8*)(lB + (wc * 32 + n * 16 + lrow) * 128 + swz);
#pragma unroll
            for (int m = 0; m < 4; ++m)
#pragma unroll
                for (int n = 0; n < 2; ++n)
                    acc[m][n] = __builtin_amdgcn_mfma_f32_16x16x32_bf16(
                        a[m], b[n], acc[m][n], 0, 0, 0);
        }
        __builtin_amdgcn_s_setprio(0);
    };

    // --- prologue ---
    LOADR(0, sAa, sAb);                 // 8 out
    LOADR(1, sBa, sBb);                 // 16 out
    asm volatile("s_waitcnt vmcnt(8)" ::: "memory");   // set A landed
    __builtin_amdgcn_sched_barrier(0);
    WRITE(0, sAa, sAb);
    LOADR(2, sAa, sAb);                 // reissue into A
    asm volatile("s_waitcnt lgkmcnt(0)" ::: "memory");
    __builtin_amdgcn_sched_barrier(0);
    __builtin_amdgcn_s_barrier();       // buf0 ready

    // --- main loop: tile t in buf t&1; tile t+1 in set (t even: B, odd: A) ---
#define STEP(T, SA, SB, VMC)                                          \
    COMPUTE(T & 1);                                                   \
    asm volatile("s_waitcnt vmcnt(" #VMC ")" ::: "memory");           \
    __builtin_amdgcn_sched_barrier(0);                                \
    WRITE((T + 1) & 1, SA, SB);                                       \
    if ((T) <= 4) LOADR((T) + 3, SA, SB);                             \
    asm volatile("s_waitcnt lgkmcnt(0)" ::: "memory");                \
    __builtin_amdgcn_sched_barrier(0);                                \
    __builtin_amdgcn_s_barrier();

    STEP(0, sBa, sBb, 8)
    STEP(1, sAa, sAb, 8)
    STEP(2, sBa, sBb, 8)
    STEP(3, sAa, sAb, 8)
    STEP(4, sBa, sBb, 8)
    STEP(5, sAa, sAb, 8)
    STEP(6, sBa, sBb, 0)
    COMPUTE(1);                         // tile 7
#undef STEP

    // --- epilogue: bf16 partials ---
    unsigned short* P = partial + (size_t)sp * (BATCH * NPAD);
#pragma unroll
    for (int m = 0; m < 4; ++m)
#pragma unroll
        for (int n = 0; n < 2; ++n)
#pragma unroll
            for (int reg = 0; reg < 4; ++reg) {
                int r = arow0 + wr * 64 + m * 16 + lgrp * 4 + reg;
                int c = brow0 + wc * 32 + n * 16 + lrow;
                P[(size_t)r * NPAD + c] = f2bf(acc[m][n][reg]);
            }
}

// ---------------- fused: split-K reduce + bias + tanh + FWHT + inv + norm ----
// One block per batch row. dot[c] = sum_j h[j]*H[c][j+1] = FWHT(g)[c] with
// g[0]=0, g[k]=h[k-1]  (Sylvester H symmetric; H[c][0]*g[0]=0 drops out).
__global__ __launch_bounds__(256) void k_fused(const unsigned short* __restrict__ partial,
                                               const float* __restrict__ bias,
                                               const float* __restrict__ epsp,
                                               const float* __restrict__ powp,
                                               float* __restrict__ out) {
    __shared__ float g[1024];
    __shared__ float wsum[4];
    const int r = blockIdx.x, t = threadIdx.x;
    const int n0 = t * 4;

    f32x4 v = {0.0f, 0.0f, 0.0f, 0.0f};
#pragma unroll
    for (int s = 0; s < SPLITK; ++s) {
        ushort4 p = *(const ushort4*)(partial + ((size_t)s * BATCH + r) * NPAD + n0);
        v[0] += bf2f(p.x); v[1] += bf2f(p.y); v[2] += bf2f(p.z); v[3] += bf2f(p.w);
    }
    float bb[4];
    if (t < 255) {
        float4 b4 = *(const float4*)(bias + n0);
        bb[0] = b4.x; bb[1] = b4.y; bb[2] = b4.z; bb[3] = b4.w;
    } else {
        bb[0] = bias[1020]; bb[1] = bias[1021]; bb[2] = bias[1022]; bb[3] = 0.0f;
    }
    if (t == 0) g[0] = 0.0f;
#pragma unroll
    for (int j = 0; j < 4; ++j) {
        int n = n0 + j;
        if (n < LOUT) g[n + 1] = tanhf(v[j] + bb[j]);
    }
    __syncthreads();

    // FWHT: 10 stages, 512 butterflies/stage, 2 per thread
#pragma unroll 1
    for (int s = 0; s < 10; ++s) {
        int st = 1 << s;
#pragma unroll
        for (int pp = 0; pp < 2; ++pp) {
            int p = t + pp * 256;
            int idx = ((p >> s) << (s + 1)) | (p & (st - 1));
            float a = g[idx], c = g[idx + st];
            g[idx] = a + c;
            g[idx + st] = a - c;
        }
        __syncthreads();
    }

    const float eps = *epsp, pw = *powp;
    float iv[4];
    float ss = 0.0f;
#pragma unroll
    for (int j = 0; j < 4; ++j) {
        int c = n0 + j;
        float d = fmaxf(1023.0f - g[c], eps);
        float q = (pw == 1.0f) ? (1.0f / d) : powf(d, -pw);
        if (c >= NCLS) q = 0.0f;
        iv[j] = q;
        ss += q;
    }
#pragma unroll
    for (int m = 32; m; m >>= 1) ss += __shfl_xor(ss, m, 64);
    if ((t & 63) == 0) wsum[t >> 6] = ss;
    __syncthreads();
    float sc = 1.0f / (wsum[0] + wsum[1] + wsum[2] + wsum[3]);

    if (n0 < NCLS) {  // NCLS = 1000 = 4*250: threads 0..249 store full float4
        float4 o;
        o.x = iv[0] * sc; o.y = iv[1] * sc; o.z = iv[2] * sc; o.w = iv[3] * sc;
        *(float4*)(out + (size_t)r * NCLS + n0) = o;
    }
}

extern "C" void kernel_launch(void* const* d_in, const int* in_sizes, int n_in,
                              void* d_out, int out_size, void* d_ws, size_t ws_size,
                              hipStream_t stream) {
    const float* x = (const float*)d_in[0];       // (512, 4096)
    const float* W = (const float*)d_in[1];       // (1023, 4096)
    const float* b = (const float*)d_in[2];       // (1023,)
    // d_in[3] = labels: NOT needed (Hadamard structure -> FWHT)
    const float* epsp = (const float*)d_in[4];
    const float* powp = (const float*)d_in[5];
    float* out = (float*)d_out;                   // (512, 1000)

    unsigned char* ws = (unsigned char*)d_ws;
    unsigned short* partial = (unsigned short*)ws;  // 8 MB (8 x 512 x 1024 bf16)

    k_gemm<<<256, 512, 0, stream>>>(x, W, partial);
    k_fused<<<512, 256, 0, stream>>>(partial, b, epsp, powp, out);
}